// Round 9
// baseline (378.272 us; speedup 1.0000x reference)
//
#include <hip/hip_runtime.h>
#include <hip/hip_bf16.h>

#define NN 100000
#define NE 1600000
#define GD 128
#define H1 64
#define H2 64
#define NREL 8
#define NBASES 30
#define NBTOT 576   // 8*64 (relations) + 64 (root)

#define NPB 256                               // nodes per bucket
#define NBUCK ((NN + NPB - 1) / NPB)          // 391
#define NWGA 128
#define ECHUNK ((NE + NWGA - 1) / NWGA)       // 12500

typedef __attribute__((ext_vector_type(8))) short bf16x8;
typedef __attribute__((ext_vector_type(4))) float f32x4;

static __device__ __forceinline__ unsigned short f2bf(float x) {
    __hip_bfloat16 h = __float2bfloat16(x);
    return *reinterpret_cast<unsigned short*>(&h);
}
static __device__ __forceinline__ float bf2f(unsigned short u) {
    return __uint_as_float(((unsigned)u) << 16);
}

// ---------- prep: WcatT[576][128] bf16 (B^T layout), B2T[64][128] bf16 ----------
__global__ void prep_kernel(const float* __restrict__ basis,   // [30][128][64]
                            const float* __restrict__ comp,    // [8][30]
                            const float* __restrict__ root,    // [128][64]
                            const float* __restrict__ w_rel,   // [64][64]
                            const float* __restrict__ w_root,  // [64][64]
                            unsigned short* __restrict__ WcatT, // [576][128] bf16
                            unsigned short* __restrict__ B2T)   // [64][128] bf16
{
    int idx = blockIdx.x * blockDim.x + threadIdx.x;
    const int totalW = NBTOT * GD;          // 73728
    if (idx < totalW) {
        int c = idx / GD;       // output col 0..575
        int i = idx % GD;       // k 0..127
        float v;
        if (c < NREL * H1) {
            int r = c >> 6, o = c & 63;
            float acc = 0.f;
            #pragma unroll 5
            for (int b = 0; b < NBASES; ++b)
                acc += comp[r * NBASES + b] * basis[(b * GD + i) * H1 + o];
            v = acc;
        } else {
            v = root[i * H1 + (c - NREL * H1)];
        }
        WcatT[idx] = f2bf(v);
    } else {
        int j = idx - totalW;               // 0..8191
        if (j < H2 * GD) {
            int o = j / GD, i = j % GD;
            float v = (i < H1) ? w_rel[i * H2 + o] : w_root[(i - H1) * H2 + o];
            B2T[j] = f2bf(v);
        }
    }
}

// ---------- bucket histogram ----------
__global__ __launch_bounds__(512)
void bucket_count(const int* __restrict__ ei, unsigned* __restrict__ bcnt)
{
    __shared__ unsigned l[NBUCK];
    int t = threadIdx.x;
    int c0 = blockIdx.x * ECHUNK;
    int c1 = c0 + ECHUNK; if (c1 > NE) c1 = NE;
    for (int i = t; i < NBUCK; i += 512) l[i] = 0;
    __syncthreads();
    for (int e = c0 + t; e < c1; e += 512)
        atomicAdd(&l[ei[NE + e] >> 8], 1u);
    __syncthreads();
    for (int i = t; i < NBUCK; i += 512)
        if (l[i]) atomicAdd(&bcnt[i], l[i]);
}

// ---------- scan 391 bucket counts ----------
__global__ __launch_bounds__(512)
void bucket_scan(const unsigned* __restrict__ bcnt,
                 unsigned* __restrict__ boff,
                 unsigned* __restrict__ bcur,
                 unsigned* __restrict__ off)
{
    __shared__ unsigned s[512];
    int t = threadIdx.x;
    unsigned v = (t < NBUCK) ? bcnt[t] : 0u;
    s[t] = v;
    __syncthreads();
    for (int st = 1; st < 512; st <<= 1) {
        unsigned u = (t >= st) ? s[t - st] : 0u;
        __syncthreads();
        s[t] += u;
        __syncthreads();
    }
    if (t < NBUCK) { boff[t] = s[t] - v; bcur[t] = s[t] - v; }
    if (t == 511) { boff[NBUCK] = s[511]; off[NN] = s[511]; }
}

// ---------- partition phase A ----------
__global__ __launch_bounds__(512)
void partition_a(const int* __restrict__ ei, const int* __restrict__ et,
                 const float* __restrict__ enorm,
                 unsigned* __restrict__ bcur,
                 uint2* __restrict__ tmp)
{
    __shared__ unsigned lcnt[NBUCK], wbase[NBUCK], lcur[NBUCK];
    int t = threadIdx.x;
    int c0 = blockIdx.x * ECHUNK;
    int c1 = c0 + ECHUNK; if (c1 > NE) c1 = NE;
    for (int i = t; i < NBUCK; i += 512) { lcnt[i] = 0; lcur[i] = 0; }
    __syncthreads();
    for (int e = c0 + t; e < c1; e += 512) {
        int dst = ei[NE + e];
        atomicAdd(&lcnt[dst >> 8], 1u);
    }
    __syncthreads();
    for (int i = t; i < NBUCK; i += 512)
        wbase[i] = atomicAdd(&bcur[i], lcnt[i]);
    __syncthreads();
    for (int e = c0 + t; e < c1; e += 512) {
        int src = ei[e], dst = ei[NE + e], r = et[e];
        int b = dst >> 8;
        unsigned pos = wbase[b] + atomicAdd(&lcur[b], 1u);
        unsigned dl = (unsigned)(dst & (NPB - 1));
        tmp[pos] = make_uint2((dl << 24) | ((unsigned)src << 3) | (unsigned)r,
                              __float_as_uint(enorm[e]));
    }
}

// ---------- partition phase B: count + scan + scatter, writes off/cnt ----------
__global__ __launch_bounds__(512)
void partition_b(const unsigned* __restrict__ boff,
                 const uint2* __restrict__ tmp,
                 uint2* __restrict__ csr,
                 unsigned* __restrict__ off,
                 unsigned* __restrict__ cnt)
{
    __shared__ unsigned lcnt[NPB * NREL];   // 8 KB
    __shared__ unsigned sscan[256];
    __shared__ unsigned lcur[NPB];
    int b = blockIdx.x, t = threadIdx.x;
    int nlo = b * NPB;
    int nn = NN - nlo; if (nn > NPB) nn = NPB;
    for (int i = t; i < NPB * NREL; i += 512) lcnt[i] = 0;
    __syncthreads();
    unsigned bstart = boff[b], bend = boff[b + 1];
    for (unsigned j = bstart + t; j < bend; j += 512) {
        unsigned x = tmp[j].x;
        atomicAdd(&lcnt[((x >> 24) << 3) | (x & 7u)], 1u);
    }
    __syncthreads();
    unsigned tot = 0;
    if (t < 256) {
        if (t < nn) {
            #pragma unroll
            for (int r = 0; r < NREL; ++r) tot += lcnt[t * NREL + r];
        }
        sscan[t] = tot;
    }
    __syncthreads();
    for (int st = 1; st < 256; st <<= 1) {
        unsigned u = (t < 256 && t >= st) ? sscan[t - st] : 0u;
        __syncthreads();
        if (t < 256) sscan[t] += u;
        __syncthreads();
    }
    if (t < nn) {
        unsigned ex = bstart + sscan[t] - tot;
        off[nlo + t] = ex;
        lcur[t] = ex;
        *reinterpret_cast<uint4*>(&cnt[(size_t)(nlo + t) * NREL]) =
            *reinterpret_cast<uint4*>(&lcnt[t * NREL]);
        *reinterpret_cast<uint4*>(&cnt[(size_t)(nlo + t) * NREL + 4]) =
            *reinterpret_cast<uint4*>(&lcnt[t * NREL + 4]);
    }
    __syncthreads();
    for (unsigned j = bstart + t; j < bend; j += 512) {
        uint2 rec = tmp[j];
        unsigned dl = rec.x >> 24;
        unsigned p = atomicAdd(&lcur[dl], 1u);
        csr[p] = make_uint2(rec.x & 0x00FFFFFFu, rec.y);
    }
}

// ---------- MFMA GEMM, BM=64 tile, barrier-free N-loop ----------
// A staged in LDS (swizzled) once; B fragments loaded global->reg per nt (L2-hot).
// Swapped-operand MFMA: D row = lane&15, col = (lane>>4)*4 + reg.
// MODE 0 (NT=9, A fp32): nt<8 -> y bf16 [N][512]; nt==8 -> root1b bf16 (+bias1)
// MODE 1 (NT=1, A bf16): out fp32 [N][64] (+b_rel)
template<int MODE>
__global__ __launch_bounds__(256)
void mfma_gemm(const void* __restrict__ Avoid,
               const unsigned short* __restrict__ Bt,
               int M,
               const float* __restrict__ bias,
               unsigned short* __restrict__ y,
               unsigned short* __restrict__ root1b,
               float* __restrict__ out)
{
    constexpr int NT = (MODE == 0) ? 9 : 1;
    __shared__ unsigned short Alds[64 * 128];   // 16 KB, swizzled

    int tid = threadIdx.x;
    int m0 = blockIdx.x * 64;
    int w = tid >> 6, l = tid & 63;
    int lr = l & 15, lk = l >> 4;

    if (MODE == 0) {
        const float* A = (const float*)Avoid;
        #pragma unroll
        for (int p = 0; p < 8; ++p) {
            int f = p * 256 + tid;          // 0..2047 float4s
            int r = f >> 5;                 // row 0..63
            int c4 = f & 31;                // float4 col 0..31
            float4 av = make_float4(0.f, 0.f, 0.f, 0.f);
            if (m0 + r < M)
                av = *reinterpret_cast<const float4*>(&A[(size_t)(m0 + r) * GD + c4 * 4]);
            ushort4 bv;
            bv.x = f2bf(av.x); bv.y = f2bf(av.y); bv.z = f2bf(av.z); bv.w = f2bf(av.w);
            int slot = (c4 >> 1) ^ (r & 7);
            int byte = r * 256 + (slot << 4) + ((c4 & 1) << 3);
            *reinterpret_cast<ushort4*>(reinterpret_cast<char*>(Alds) + byte) = bv;
        }
    } else {
        const unsigned short* A = (const unsigned short*)Avoid;
        #pragma unroll
        for (int p = 0; p < 4; ++p) {
            int f = p * 256 + tid;          // 0..1023 16B-chunks
            int r = f >> 4;                 // row 0..63
            int slot = f & 15;
            uint4 v = make_uint4(0u, 0u, 0u, 0u);
            if (m0 + r < M)
                v = *reinterpret_cast<const uint4*>(&A[(size_t)(m0 + r) * GD + slot * 8]);
            int byte = r * 256 + ((slot ^ (r & 7)) << 4);
            *reinterpret_cast<uint4*>(reinterpret_cast<char*>(Alds) + byte) = v;
        }
    }
    __syncthreads();   // the ONLY barrier — Alds is read-only afterwards

    #pragma unroll 1
    for (int i = 0; i < NT; ++i) {
        int nt = (MODE == 0) ? (int)((i + blockIdx.x) % 9u) : 0;   // stagger L2 sets
        f32x4 acc[4];
        #pragma unroll
        for (int j = 0; j < 4; ++j)
            acc[j] = (f32x4){0.f, 0.f, 0.f, 0.f};

        #pragma unroll
        for (int ks = 0; ks < 4; ++ks) {
            int q = 4 * ks + lk;
            int sA = q ^ (lr & 7);
            bf16x8 a0 = *reinterpret_cast<const bf16x8*>(
                reinterpret_cast<char*>(Alds) + (w * 16 + lr) * 256 + (sA << 4));
            #pragma unroll
            for (int cf = 0; cf < 4; ++cf) {
                // B fragment straight from global (L2-resident, full-line pattern)
                bf16x8 b = *reinterpret_cast<const bf16x8*>(
                    &Bt[(size_t)(nt * 64 + cf * 16 + lr) * GD + q * 8]);
                acc[cf] = __builtin_amdgcn_mfma_f32_16x16x32_bf16(b, a0, acc[cf], 0, 0, 0);
            }
        }

        int row = m0 + w * 16 + lr;
        if (row < M) {
            #pragma unroll
            for (int cf = 0; cf < 4; ++cf) {
                int cb = cf * 16 + lk * 4;      // col within 64-wide tile
                f32x4 v = acc[cf];
                if (MODE == 0) {
                    if (nt < 8) {
                        ushort4 pv;
                        pv.x = f2bf(v[0]); pv.y = f2bf(v[1]);
                        pv.z = f2bf(v[2]); pv.w = f2bf(v[3]);
                        *reinterpret_cast<ushort4*>(&y[(size_t)row * 512 + nt * 64 + cb]) = pv;
                    } else {
                        float4 bb = *reinterpret_cast<const float4*>(&bias[cb]);
                        ushort4 pv;
                        pv.x = f2bf(v[0] + bb.x); pv.y = f2bf(v[1] + bb.y);
                        pv.z = f2bf(v[2] + bb.z); pv.w = f2bf(v[3] + bb.w);
                        *reinterpret_cast<ushort4*>(&root1b[(size_t)row * 64 + cb]) = pv;
                    }
                } else {
                    float4 bb = *reinterpret_cast<const float4*>(&bias[cb]);
                    float4 ov;
                    ov.x = v[0] + bb.x; ov.y = v[1] + bb.y;
                    ov.z = v[2] + bb.z; ov.w = v[3] + bb.w;
                    *reinterpret_cast<float4*>(&out[(size_t)row * 64 + cb]) = ov;
                }
            }
        }
    }
}

// ---------- RGCN aggregate: wave per node, lane = h1 dim, 4-deep MLP ----------
__global__ void rgcn_aggregate(const unsigned* __restrict__ off,
                               const uint2* __restrict__ csr,
                               const unsigned* __restrict__ cnt,
                               const unsigned short* __restrict__ y,
                               const unsigned short* __restrict__ root1b,
                               unsigned short* __restrict__ abuf)
{
    int gid = blockIdx.x * blockDim.x + threadIdx.x;
    int n = gid >> 6;
    int lane = gid & 63;
    if (n >= NN) return;
    unsigned myc = (lane < NREL) ? cnt[(size_t)n * NREL + lane] : 1u;
    float myinv = 1.0f / (float)(myc > 0u ? myc : 1u);
    unsigned s = off[n], e = off[n + 1];
    float a0 = 0.f, a1 = 0.f, a2 = 0.f, a3 = 0.f;
    unsigned i = s;
    for (; i + 4 <= e; i += 4) {
        uint2 q0 = csr[i], q1 = csr[i + 1], q2 = csr[i + 2], q3 = csr[i + 3];
        float v0 = bf2f(y[(size_t)q0.x * 64 + lane]);
        float v1 = bf2f(y[(size_t)q1.x * 64 + lane]);
        float v2 = bf2f(y[(size_t)q2.x * 64 + lane]);
        float v3 = bf2f(y[(size_t)q3.x * 64 + lane]);
        a0 += v0 * __shfl(myinv, (int)(q0.x & 7));
        a1 += v1 * __shfl(myinv, (int)(q1.x & 7));
        a2 += v2 * __shfl(myinv, (int)(q2.x & 7));
        a3 += v3 * __shfl(myinv, (int)(q3.x & 7));
    }
    for (; i < e; ++i) {
        uint2 q = csr[i];
        a0 += bf2f(y[(size_t)q.x * 64 + lane]) * __shfl(myinv, (int)(q.x & 7));
    }
    float out1 = bf2f(root1b[(size_t)n * 64 + lane]) + ((a0 + a1) + (a2 + a3));
    abuf[(size_t)n * 128 + 64 + lane] = f2bf(out1);
}

// ---------- GraphConv aggregate: 4-deep MLP ----------
__global__ void graph_aggregate(const unsigned* __restrict__ off,
                                const uint2* __restrict__ csr,
                                unsigned short* __restrict__ abuf)
{
    int gid = blockIdx.x * blockDim.x + threadIdx.x;
    int n = gid >> 6;
    int lane = gid & 63;
    if (n >= NN) return;
    unsigned s = off[n], e = off[n + 1];
    float a0 = 0.f, a1 = 0.f, a2 = 0.f, a3 = 0.f;
    unsigned i = s;
    for (; i + 4 <= e; i += 4) {
        uint2 q0 = csr[i], q1 = csr[i + 1], q2 = csr[i + 2], q3 = csr[i + 3];
        float v0 = bf2f(abuf[(size_t)(q0.x >> 3) * 128 + 64 + lane]);
        float v1 = bf2f(abuf[(size_t)(q1.x >> 3) * 128 + 64 + lane]);
        float v2 = bf2f(abuf[(size_t)(q2.x >> 3) * 128 + 64 + lane]);
        float v3 = bf2f(abuf[(size_t)(q3.x >> 3) * 128 + 64 + lane]);
        a0 += v0 * __uint_as_float(q0.y);
        a1 += v1 * __uint_as_float(q1.y);
        a2 += v2 * __uint_as_float(q2.y);
        a3 += v3 * __uint_as_float(q3.y);
    }
    for (; i < e; ++i) {
        uint2 q = csr[i];
        a0 += bf2f(abuf[(size_t)(q.x >> 3) * 128 + 64 + lane]) * __uint_as_float(q.y);
    }
    abuf[(size_t)n * 128 + lane] = f2bf(((a0 + a1) + (a2 + a3)));
}

extern "C" void kernel_launch(void* const* d_in, const int* in_sizes, int n_in,
                              void* d_out, int out_size, void* d_ws, size_t ws_size,
                              hipStream_t stream)
{
    const float* node_features = (const float*)d_in[0];
    const int*   edge_index    = (const int*)d_in[1];
    const float* edge_norm     = (const float*)d_in[2];
    const int*   edge_type     = (const int*)d_in[3];
    const float* basis         = (const float*)d_in[4];
    const float* comp          = (const float*)d_in[5];
    const float* root          = (const float*)d_in[6];
    const float* bias1         = (const float*)d_in[7];
    const float* w_rel         = (const float*)d_in[8];
    const float* b_rel         = (const float*)d_in[9];
    const float* w_root        = (const float*)d_in[10];
    float* out = (float*)d_out;

    char* ws = (char*)d_ws;
    size_t o = 0;
    auto alloc = [&](size_t bytes) -> void* {
        o = (o + 511) & ~(size_t)511;
        void* p = ws + o;
        o += bytes;
        return p;
    };
    unsigned short* WcatT = (unsigned short*)alloc((size_t)NBTOT * GD * 2);
    unsigned short* B2T   = (unsigned short*)alloc((size_t)H2 * GD * 2);
    unsigned* cnt      = (unsigned*)alloc((size_t)NN * NREL * 4);
    unsigned* off_     = (unsigned*)alloc((size_t)(NN + 1) * 4);
    unsigned* bcnt     = (unsigned*)alloc((size_t)NBUCK * 4);
    unsigned* boff     = (unsigned*)alloc((size_t)(NBUCK + 1) * 4);
    unsigned* bcur     = (unsigned*)alloc((size_t)NBUCK * 4);
    uint2*    csr      = (uint2*)alloc((size_t)NE * 8);
    unsigned short* y  = (unsigned short*)alloc((size_t)NN * 512 * 2);
    unsigned short* root1b = (unsigned short*)alloc((size_t)NN * 64 * 2);
    unsigned short* abuf = (unsigned short*)alloc((size_t)NN * 128 * 2);
    uint2*    tmp      = (uint2*)abuf;   // alias: tmp dead before abuf's first write

    hipMemsetAsync(bcnt, 0, (size_t)NBUCK * 4, stream);

    prep_kernel<<<(NBTOT * GD + H2 * GD + 255) / 256, 256, 0, stream>>>(
        basis, comp, root, w_rel, w_root, WcatT, B2T);

    bucket_count<<<NWGA, 512, 0, stream>>>(edge_index, bcnt);
    bucket_scan<<<1, 512, 0, stream>>>(bcnt, boff, bcur, off_);
    partition_a<<<NWGA, 512, 0, stream>>>(edge_index, edge_type, edge_norm, bcur, tmp);
    partition_b<<<NBUCK, 512, 0, stream>>>(boff, tmp, csr, off_, cnt);

    int gblk = (NN + 63) / 64;   // 1563
    mfma_gemm<0><<<gblk, 256, 0, stream>>>(node_features, WcatT, NN, bias1, y, root1b, nullptr);

    rgcn_aggregate<<<(NN * 64 + 255) / 256, 256, 0, stream>>>(off_, csr, cnt, y, root1b, abuf);

    graph_aggregate<<<(NN * 64 + 255) / 256, 256, 0, stream>>>(off_, csr, abuf);

    mfma_gemm<1><<<gblk, 256, 0, stream>>>(abuf, B2T, NN, b_rel, nullptr, nullptr, out);
}

// Round 10
// 296.397 us; speedup vs baseline: 1.2762x; 1.2762x over previous
//
#include <hip/hip_runtime.h>
#include <hip/hip_bf16.h>

#define NN 100000
#define NE 1600000
#define GD 128
#define H1 64
#define H2 64
#define NREL 8
#define NBASES 30
#define NBTOT 576   // 8*64 (relations) + 64 (root)

#define NPB 256                               // nodes per bucket
#define NBUCK ((NN + NPB - 1) / NPB)          // 391
#define NWGA 128
#define ECHUNK ((NE + NWGA - 1) / NWGA)       // 12500

typedef __attribute__((ext_vector_type(8))) short bf16x8;
typedef __attribute__((ext_vector_type(4))) float f32x4;

static __device__ __forceinline__ unsigned short f2bf(float x) {
    __hip_bfloat16 h = __float2bfloat16(x);
    return *reinterpret_cast<unsigned short*>(&h);
}
static __device__ __forceinline__ float bf2f(unsigned short u) {
    return __uint_as_float(((unsigned)u) << 16);
}

// ---------- prep: WcatT[576][128] bf16 (B^T layout), B2T[64][128] bf16 ----------
__global__ void prep_kernel(const float* __restrict__ basis,   // [30][128][64]
                            const float* __restrict__ comp,    // [8][30]
                            const float* __restrict__ root,    // [128][64]
                            const float* __restrict__ w_rel,   // [64][64]
                            const float* __restrict__ w_root,  // [64][64]
                            unsigned short* __restrict__ WcatT, // [576][128] bf16
                            unsigned short* __restrict__ B2T)   // [64][128] bf16
{
    int idx = blockIdx.x * blockDim.x + threadIdx.x;
    const int totalW = NBTOT * GD;          // 73728
    if (idx < totalW) {
        int c = idx / GD;       // output col 0..575
        int i = idx % GD;       // k 0..127
        float v;
        if (c < NREL * H1) {
            int r = c >> 6, o = c & 63;
            float acc = 0.f;
            #pragma unroll 5
            for (int b = 0; b < NBASES; ++b)
                acc += comp[r * NBASES + b] * basis[(b * GD + i) * H1 + o];
            v = acc;
        } else {
            v = root[i * H1 + (c - NREL * H1)];
        }
        WcatT[idx] = f2bf(v);
    } else {
        int j = idx - totalW;               // 0..8191
        if (j < H2 * GD) {
            int o = j / GD, i = j % GD;
            float v = (i < H1) ? w_rel[i * H2 + o] : w_root[(i - H1) * H2 + o];
            B2T[j] = f2bf(v);
        }
    }
}

// ---------- bucket histogram ----------
__global__ __launch_bounds__(512)
void bucket_count(const int* __restrict__ ei, unsigned* __restrict__ bcnt)
{
    __shared__ unsigned l[NBUCK];
    int t = threadIdx.x;
    int c0 = blockIdx.x * ECHUNK;
    int c1 = c0 + ECHUNK; if (c1 > NE) c1 = NE;
    for (int i = t; i < NBUCK; i += 512) l[i] = 0;
    __syncthreads();
    for (int e = c0 + t; e < c1; e += 512)
        atomicAdd(&l[ei[NE + e] >> 8], 1u);
    __syncthreads();
    for (int i = t; i < NBUCK; i += 512)
        if (l[i]) atomicAdd(&bcnt[i], l[i]);
}

// ---------- scan 391 bucket counts ----------
__global__ __launch_bounds__(512)
void bucket_scan(const unsigned* __restrict__ bcnt,
                 unsigned* __restrict__ boff,
                 unsigned* __restrict__ bcur,
                 unsigned* __restrict__ off)
{
    __shared__ unsigned s[512];
    int t = threadIdx.x;
    unsigned v = (t < NBUCK) ? bcnt[t] : 0u;
    s[t] = v;
    __syncthreads();
    for (int st = 1; st < 512; st <<= 1) {
        unsigned u = (t >= st) ? s[t - st] : 0u;
        __syncthreads();
        s[t] += u;
        __syncthreads();
    }
    if (t < NBUCK) { boff[t] = s[t] - v; bcur[t] = s[t] - v; }
    if (t == 511) { boff[NBUCK] = s[511]; off[NN] = s[511]; }
}

// ---------- partition phase A ----------
__global__ __launch_bounds__(512)
void partition_a(const int* __restrict__ ei, const int* __restrict__ et,
                 const float* __restrict__ enorm,
                 unsigned* __restrict__ bcur,
                 uint2* __restrict__ tmp)
{
    __shared__ unsigned lcnt[NBUCK], wbase[NBUCK], lcur[NBUCK];
    int t = threadIdx.x;
    int c0 = blockIdx.x * ECHUNK;
    int c1 = c0 + ECHUNK; if (c1 > NE) c1 = NE;
    for (int i = t; i < NBUCK; i += 512) { lcnt[i] = 0; lcur[i] = 0; }
    __syncthreads();
    for (int e = c0 + t; e < c1; e += 512) {
        int dst = ei[NE + e];
        atomicAdd(&lcnt[dst >> 8], 1u);
    }
    __syncthreads();
    for (int i = t; i < NBUCK; i += 512)
        wbase[i] = atomicAdd(&bcur[i], lcnt[i]);
    __syncthreads();
    for (int e = c0 + t; e < c1; e += 512) {
        int src = ei[e], dst = ei[NE + e], r = et[e];
        int b = dst >> 8;
        unsigned pos = wbase[b] + atomicAdd(&lcur[b], 1u);
        unsigned dl = (unsigned)(dst & (NPB - 1));
        tmp[pos] = make_uint2((dl << 24) | ((unsigned)src << 3) | (unsigned)r,
                              __float_as_uint(enorm[e]));
    }
}

// ---------- partition phase B: count + scan + scatter, writes off/cnt ----------
__global__ __launch_bounds__(512)
void partition_b(const unsigned* __restrict__ boff,
                 const uint2* __restrict__ tmp,
                 uint2* __restrict__ csr,
                 unsigned* __restrict__ off,
                 unsigned* __restrict__ cnt)
{
    __shared__ unsigned lcnt[NPB * NREL];   // 8 KB
    __shared__ unsigned sscan[256];
    __shared__ unsigned lcur[NPB];
    int b = blockIdx.x, t = threadIdx.x;
    int nlo = b * NPB;
    int nn = NN - nlo; if (nn > NPB) nn = NPB;
    for (int i = t; i < NPB * NREL; i += 512) lcnt[i] = 0;
    __syncthreads();
    unsigned bstart = boff[b], bend = boff[b + 1];
    for (unsigned j = bstart + t; j < bend; j += 512) {
        unsigned x = tmp[j].x;
        atomicAdd(&lcnt[((x >> 24) << 3) | (x & 7u)], 1u);
    }
    __syncthreads();
    unsigned tot = 0;
    if (t < 256) {
        if (t < nn) {
            #pragma unroll
            for (int r = 0; r < NREL; ++r) tot += lcnt[t * NREL + r];
        }
        sscan[t] = tot;
    }
    __syncthreads();
    for (int st = 1; st < 256; st <<= 1) {
        unsigned u = (t < 256 && t >= st) ? sscan[t - st] : 0u;
        __syncthreads();
        if (t < 256) sscan[t] += u;
        __syncthreads();
    }
    if (t < nn) {
        unsigned ex = bstart + sscan[t] - tot;
        off[nlo + t] = ex;
        lcur[t] = ex;
        *reinterpret_cast<uint4*>(&cnt[(size_t)(nlo + t) * NREL]) =
            *reinterpret_cast<uint4*>(&lcnt[t * NREL]);
        *reinterpret_cast<uint4*>(&cnt[(size_t)(nlo + t) * NREL + 4]) =
            *reinterpret_cast<uint4*>(&lcnt[t * NREL + 4]);
    }
    __syncthreads();
    for (unsigned j = bstart + t; j < bend; j += 512) {
        uint2 rec = tmp[j];
        unsigned dl = rec.x >> 24;
        unsigned p = atomicAdd(&lcur[dl], 1u);
        csr[p] = make_uint2(rec.x & 0x00FFFFFFu, rec.y);
    }
}

// ---------- MFMA GEMM: BM=128, LDS A+B, reg-prefetched B, raw barriers ----------
// Swapped-operand MFMA: D row = lane&15, col = (lane>>4)*4 + reg.
// MODE 0 (NT=9, A fp32): nt<8 -> y bf16 [N][512]; nt==8 -> root1b bf16 (+bias1)
// MODE 1 (NT=1, A bf16): out fp32 [N][64] (+b_rel)
// Barriers are raw s_barrier with lgkmcnt(0) only — output stores and prefetch
// loads are NEVER vmcnt-drained in the loop (T4).
template<int MODE>
__global__ __launch_bounds__(256)
void mfma_gemm(const void* __restrict__ Avoid,
               const unsigned short* __restrict__ Bt,
               int M,
               const float* __restrict__ bias,
               unsigned short* __restrict__ y,
               unsigned short* __restrict__ root1b,
               float* __restrict__ out)
{
    constexpr int NT = (MODE == 0) ? 9 : 1;
    __shared__ unsigned short Alds[128 * 128];   // 32 KB, swizzled
    __shared__ unsigned short Blds[64 * 128];    // 16 KB, swizzled

    int tid = threadIdx.x;
    int m0 = blockIdx.x * 128;
    int w = tid >> 6, l = tid & 63;
    int lr = l & 15, lk = l >> 4;

    // ---- prologue: issue B(nt=0) loads first (latency hides under A-stage) ----
    uint4 breg0, breg1, breg2, breg3;
    {
        int c0 = (0 * 256 + tid) >> 4, s0 = tid & 15;
        int c1 = (1 * 256 + tid) >> 4, s1 = tid & 15;
        int c2 = (2 * 256 + tid) >> 4, s2 = tid & 15;
        int c3 = (3 * 256 + tid) >> 4, s3 = tid & 15;
        breg0 = *reinterpret_cast<const uint4*>(&Bt[(size_t)c0 * GD + s0 * 8]);
        breg1 = *reinterpret_cast<const uint4*>(&Bt[(size_t)c1 * GD + s1 * 8]);
        breg2 = *reinterpret_cast<const uint4*>(&Bt[(size_t)c2 * GD + s2 * 8]);
        breg3 = *reinterpret_cast<const uint4*>(&Bt[(size_t)c3 * GD + s3 * 8]);
    }

    // ---- A stage ----
    if (MODE == 0) {
        const float* A = (const float*)Avoid;
        #pragma unroll
        for (int p = 0; p < 16; ++p) {
            int f = p * 256 + tid;          // 0..4095 float4s
            int r = f >> 5;                 // row 0..127
            int c4 = f & 31;                // float4 col 0..31
            float4 av = make_float4(0.f, 0.f, 0.f, 0.f);
            if (m0 + r < M)
                av = *reinterpret_cast<const float4*>(&A[(size_t)(m0 + r) * GD + c4 * 4]);
            ushort4 bv;
            bv.x = f2bf(av.x); bv.y = f2bf(av.y); bv.z = f2bf(av.z); bv.w = f2bf(av.w);
            int slot = (c4 >> 1) ^ (r & 7);
            int byte = r * 256 + (slot << 4) + ((c4 & 1) << 3);
            *reinterpret_cast<ushort4*>(reinterpret_cast<char*>(Alds) + byte) = bv;
        }
    } else {
        const unsigned short* A = (const unsigned short*)Avoid;
        #pragma unroll
        for (int p = 0; p < 8; ++p) {
            int f = p * 256 + tid;          // 0..2047 16B-chunks
            int r = f >> 4;                 // row 0..127
            int slot = f & 15;
            uint4 v = make_uint4(0u, 0u, 0u, 0u);
            if (m0 + r < M)
                v = *reinterpret_cast<const uint4*>(&A[(size_t)(m0 + r) * GD + slot * 8]);
            int byte = r * 256 + ((slot ^ (r & 7)) << 4);
            *reinterpret_cast<uint4*>(reinterpret_cast<char*>(Alds) + byte) = v;
        }
    }

    // ---- write B0 into LDS (vmcnt dependency handled by compiler) ----
    {
        int c = (0 * 256 + tid) >> 4, s = tid & 15;
        *reinterpret_cast<uint4*>(reinterpret_cast<char*>(Blds) + c * 256 + ((s ^ (c & 7)) << 4)) = breg0;
        c = (1 * 256 + tid) >> 4;
        *reinterpret_cast<uint4*>(reinterpret_cast<char*>(Blds) + c * 256 + ((s ^ (c & 7)) << 4)) = breg1;
        c = (2 * 256 + tid) >> 4;
        *reinterpret_cast<uint4*>(reinterpret_cast<char*>(Blds) + c * 256 + ((s ^ (c & 7)) << 4)) = breg2;
        c = (3 * 256 + tid) >> 4;
        *reinterpret_cast<uint4*>(reinterpret_cast<char*>(Blds) + c * 256 + ((s ^ (c & 7)) << 4)) = breg3;
    }
    asm volatile("s_waitcnt lgkmcnt(0)" ::: "memory");
    __builtin_amdgcn_sched_barrier(0);
    __builtin_amdgcn_s_barrier();
    __builtin_amdgcn_sched_barrier(0);

    #pragma unroll 1
    for (int nt = 0; nt < NT; ++nt) {
        // ---- issue next tile's B loads (async, consumed after barrier) ----
        if (nt + 1 < NT) {
            int c = (0 * 256 + tid) >> 4, s = tid & 15;
            breg0 = *reinterpret_cast<const uint4*>(&Bt[(size_t)((nt + 1) * 64 + c) * GD + s * 8]);
            c = (1 * 256 + tid) >> 4;
            breg1 = *reinterpret_cast<const uint4*>(&Bt[(size_t)((nt + 1) * 64 + c) * GD + s * 8]);
            c = (2 * 256 + tid) >> 4;
            breg2 = *reinterpret_cast<const uint4*>(&Bt[(size_t)((nt + 1) * 64 + c) * GD + s * 8]);
            c = (3 * 256 + tid) >> 4;
            breg3 = *reinterpret_cast<const uint4*>(&Bt[(size_t)((nt + 1) * 64 + c) * GD + s * 8]);
        }

        // ---- compute from Alds/Blds ----
        f32x4 acc[2][4];
        #pragma unroll
        for (int i = 0; i < 2; ++i)
            #pragma unroll
            for (int j = 0; j < 4; ++j)
                acc[i][j] = (f32x4){0.f, 0.f, 0.f, 0.f};

        #pragma unroll
        for (int ks = 0; ks < 4; ++ks) {
            int q = 4 * ks + lk;
            int sA = q ^ (lr & 7);
            bf16x8 a0 = *reinterpret_cast<const bf16x8*>(
                reinterpret_cast<char*>(Alds) + (w * 32 + 0 * 16 + lr) * 256 + (sA << 4));
            bf16x8 a1 = *reinterpret_cast<const bf16x8*>(
                reinterpret_cast<char*>(Alds) + (w * 32 + 1 * 16 + lr) * 256 + (sA << 4));
            #pragma unroll
            for (int cf = 0; cf < 4; ++cf) {
                bf16x8 b = *reinterpret_cast<const bf16x8*>(
                    reinterpret_cast<char*>(Blds) + (cf * 16 + lr) * 256 + (sA << 4));
                acc[0][cf] = __builtin_amdgcn_mfma_f32_16x16x32_bf16(b, a0, acc[0][cf], 0, 0, 0);
                acc[1][cf] = __builtin_amdgcn_mfma_f32_16x16x32_bf16(b, a1, acc[1][cf], 0, 0, 0);
            }
        }

        // ---- output stores (never drained in-loop) ----
        #pragma unroll
        for (int rf = 0; rf < 2; ++rf) {
            int row = m0 + w * 32 + rf * 16 + lr;
            if (row < M) {
                #pragma unroll
                for (int cf = 0; cf < 4; ++cf) {
                    int cb = cf * 16 + lk * 4;
                    f32x4 v = acc[rf][cf];
                    if (MODE == 0) {
                        if (nt < 8) {
                            ushort4 pv;
                            pv.x = f2bf(v[0]); pv.y = f2bf(v[1]);
                            pv.z = f2bf(v[2]); pv.w = f2bf(v[3]);
                            *reinterpret_cast<ushort4*>(&y[(size_t)row * 512 + nt * 64 + cb]) = pv;
                        } else {
                            float4 bb = *reinterpret_cast<const float4*>(&bias[cb]);
                            ushort4 pv;
                            pv.x = f2bf(v[0] + bb.x); pv.y = f2bf(v[1] + bb.y);
                            pv.z = f2bf(v[2] + bb.z); pv.w = f2bf(v[3] + bb.w);
                            *reinterpret_cast<ushort4*>(&root1b[(size_t)row * 64 + cb]) = pv;
                        }
                    } else {
                        float4 bb = *reinterpret_cast<const float4*>(&bias[cb]);
                        float4 ov;
                        ov.x = v[0] + bb.x; ov.y = v[1] + bb.y;
                        ov.z = v[2] + bb.z; ov.w = v[3] + bb.w;
                        *reinterpret_cast<float4*>(&out[(size_t)row * 64 + cb]) = ov;
                    }
                }
            }
        }

        // ---- swap B buffer: barrier (all done reading) -> write -> barrier ----
        if (nt + 1 < NT) {
            asm volatile("s_waitcnt lgkmcnt(0)" ::: "memory");
            __builtin_amdgcn_sched_barrier(0);
            __builtin_amdgcn_s_barrier();
            __builtin_amdgcn_sched_barrier(0);
            int c = (0 * 256 + tid) >> 4, s = tid & 15;
            *reinterpret_cast<uint4*>(reinterpret_cast<char*>(Blds) + c * 256 + ((s ^ (c & 7)) << 4)) = breg0;
            c = (1 * 256 + tid) >> 4;
            *reinterpret_cast<uint4*>(reinterpret_cast<char*>(Blds) + c * 256 + ((s ^ (c & 7)) << 4)) = breg1;
            c = (2 * 256 + tid) >> 4;
            *reinterpret_cast<uint4*>(reinterpret_cast<char*>(Blds) + c * 256 + ((s ^ (c & 7)) << 4)) = breg2;
            c = (3 * 256 + tid) >> 4;
            *reinterpret_cast<uint4*>(reinterpret_cast<char*>(Blds) + c * 256 + ((s ^ (c & 7)) << 4)) = breg3;
            asm volatile("s_waitcnt lgkmcnt(0)" ::: "memory");
            __builtin_amdgcn_sched_barrier(0);
            __builtin_amdgcn_s_barrier();
            __builtin_amdgcn_sched_barrier(0);
        }
    }
}

// ---------- RGCN aggregate: wave per node, lane = h1 dim, 4-deep MLP ----------
__global__ void rgcn_aggregate(const unsigned* __restrict__ off,
                               const uint2* __restrict__ csr,
                               const unsigned* __restrict__ cnt,
                               const unsigned short* __restrict__ y,
                               const unsigned short* __restrict__ root1b,
                               unsigned short* __restrict__ abuf)
{
    int gid = blockIdx.x * blockDim.x + threadIdx.x;
    int n = gid >> 6;
    int lane = gid & 63;
    if (n >= NN) return;
    unsigned myc = (lane < NREL) ? cnt[(size_t)n * NREL + lane] : 1u;
    float myinv = 1.0f / (float)(myc > 0u ? myc : 1u);
    unsigned s = off[n], e = off[n + 1];
    float a0 = 0.f, a1 = 0.f, a2 = 0.f, a3 = 0.f;
    unsigned i = s;
    for (; i + 4 <= e; i += 4) {
        uint2 q0 = csr[i], q1 = csr[i + 1], q2 = csr[i + 2], q3 = csr[i + 3];
        float v0 = bf2f(y[(size_t)q0.x * 64 + lane]);
        float v1 = bf2f(y[(size_t)q1.x * 64 + lane]);
        float v2 = bf2f(y[(size_t)q2.x * 64 + lane]);
        float v3 = bf2f(y[(size_t)q3.x * 64 + lane]);
        a0 += v0 * __shfl(myinv, (int)(q0.x & 7));
        a1 += v1 * __shfl(myinv, (int)(q1.x & 7));
        a2 += v2 * __shfl(myinv, (int)(q2.x & 7));
        a3 += v3 * __shfl(myinv, (int)(q3.x & 7));
    }
    for (; i < e; ++i) {
        uint2 q = csr[i];
        a0 += bf2f(y[(size_t)q.x * 64 + lane]) * __shfl(myinv, (int)(q.x & 7));
    }
    float out1 = bf2f(root1b[(size_t)n * 64 + lane]) + ((a0 + a1) + (a2 + a3));
    abuf[(size_t)n * 128 + 64 + lane] = f2bf(out1);
}

// ---------- GraphConv aggregate: 4-deep MLP ----------
__global__ void graph_aggregate(const unsigned* __restrict__ off,
                                const uint2* __restrict__ csr,
                                unsigned short* __restrict__ abuf)
{
    int gid = blockIdx.x * blockDim.x + threadIdx.x;
    int n = gid >> 6;
    int lane = gid & 63;
    if (n >= NN) return;
    unsigned s = off[n], e = off[n + 1];
    float a0 = 0.f, a1 = 0.f, a2 = 0.f, a3 = 0.f;
    unsigned i = s;
    for (; i + 4 <= e; i += 4) {
        uint2 q0 = csr[i], q1 = csr[i + 1], q2 = csr[i + 2], q3 = csr[i + 3];
        float v0 = bf2f(abuf[(size_t)(q0.x >> 3) * 128 + 64 + lane]);
        float v1 = bf2f(abuf[(size_t)(q1.x >> 3) * 128 + 64 + lane]);
        float v2 = bf2f(abuf[(size_t)(q2.x >> 3) * 128 + 64 + lane]);
        float v3 = bf2f(abuf[(size_t)(q3.x >> 3) * 128 + 64 + lane]);
        a0 += v0 * __uint_as_float(q0.y);
        a1 += v1 * __uint_as_float(q1.y);
        a2 += v2 * __uint_as_float(q2.y);
        a3 += v3 * __uint_as_float(q3.y);
    }
    for (; i < e; ++i) {
        uint2 q = csr[i];
        a0 += bf2f(abuf[(size_t)(q.x >> 3) * 128 + 64 + lane]) * __uint_as_float(q.y);
    }
    abuf[(size_t)n * 128 + lane] = f2bf(((a0 + a1) + (a2 + a3)));
}

extern "C" void kernel_launch(void* const* d_in, const int* in_sizes, int n_in,
                              void* d_out, int out_size, void* d_ws, size_t ws_size,
                              hipStream_t stream)
{
    const float* node_features = (const float*)d_in[0];
    const int*   edge_index    = (const int*)d_in[1];
    const float* edge_norm     = (const float*)d_in[2];
    const int*   edge_type     = (const int*)d_in[3];
    const float* basis         = (const float*)d_in[4];
    const float* comp          = (const float*)d_in[5];
    const float* root          = (const float*)d_in[6];
    const float* bias1         = (const float*)d_in[7];
    const float* w_rel         = (const float*)d_in[8];
    const float* b_rel         = (const float*)d_in[9];
    const float* w_root        = (const float*)d_in[10];
    float* out = (float*)d_out;

    char* ws = (char*)d_ws;
    size_t o = 0;
    auto alloc = [&](size_t bytes) -> void* {
        o = (o + 511) & ~(size_t)511;
        void* p = ws + o;
        o += bytes;
        return p;
    };
    unsigned short* WcatT = (unsigned short*)alloc((size_t)NBTOT * GD * 2);
    unsigned short* B2T   = (unsigned short*)alloc((size_t)H2 * GD * 2);
    unsigned* cnt      = (unsigned*)alloc((size_t)NN * NREL * 4);
    unsigned* off_     = (unsigned*)alloc((size_t)(NN + 1) * 4);
    unsigned* bcnt     = (unsigned*)alloc((size_t)NBUCK * 4);
    unsigned* boff     = (unsigned*)alloc((size_t)(NBUCK + 1) * 4);
    unsigned* bcur     = (unsigned*)alloc((size_t)NBUCK * 4);
    uint2*    csr      = (uint2*)alloc((size_t)NE * 8);
    unsigned short* y  = (unsigned short*)alloc((size_t)NN * 512 * 2);
    unsigned short* root1b = (unsigned short*)alloc((size_t)NN * 64 * 2);
    unsigned short* abuf = (unsigned short*)alloc((size_t)NN * 128 * 2);
    uint2*    tmp      = (uint2*)abuf;   // alias: tmp dead before abuf's first write

    hipMemsetAsync(bcnt, 0, (size_t)NBUCK * 4, stream);

    prep_kernel<<<(NBTOT * GD + H2 * GD + 255) / 256, 256, 0, stream>>>(
        basis, comp, root, w_rel, w_root, WcatT, B2T);

    bucket_count<<<NWGA, 512, 0, stream>>>(edge_index, bcnt);
    bucket_scan<<<1, 512, 0, stream>>>(bcnt, boff, bcur, off_);
    partition_a<<<NWGA, 512, 0, stream>>>(edge_index, edge_type, edge_norm, bcur, tmp);
    partition_b<<<NBUCK, 512, 0, stream>>>(boff, tmp, csr, off_, cnt);

    int gblk = (NN + 127) / 128;   // 782
    mfma_gemm<0><<<gblk, 256, 0, stream>>>(node_features, WcatT, NN, bias1, y, root1b, nullptr);

    rgcn_aggregate<<<(NN * 64 + 255) / 256, 256, 0, stream>>>(off_, csr, cnt, y, root1b, abuf);

    graph_aggregate<<<(NN * 64 + 255) / 256, 256, 0, stream>>>(off_, csr, abuf);

    mfma_gemm<1><<<gblk, 256, 0, stream>>>(abuf, B2T, NN, b_rel, nullptr, nullptr, out);
}

// Round 11
// 248.505 us; speedup vs baseline: 1.5222x; 1.1927x over previous
//
#include <hip/hip_runtime.h>
#include <hip/hip_bf16.h>

#define NN 100000
#define NE 1600000
#define GD 128
#define H1 64
#define H2 64
#define NREL 8
#define NBASES 30
#define NBTOT 576   // 8*64 (relations) + 64 (root)

#define NPB 256                               // nodes per bucket
#define NBUCK ((NN + NPB - 1) / NPB)          // 391
#define NWGA 128
#define ECHUNK ((NE + NWGA - 1) / NWGA)       // 12500

typedef __attribute__((ext_vector_type(8))) short bf16x8;
typedef __attribute__((ext_vector_type(4))) float f32x4;

static __device__ __forceinline__ unsigned short f2bf(float x) {
    __hip_bfloat16 h = __float2bfloat16(x);
    return *reinterpret_cast<unsigned short*>(&h);
}
static __device__ __forceinline__ float bf2f(unsigned short u) {
    return __uint_as_float(((unsigned)u) << 16);
}
static __device__ __forceinline__ float bflo(unsigned u) {   // low bf16 of packed pair
    return __uint_as_float(u << 16);
}
static __device__ __forceinline__ float bfhi(unsigned u) {   // high bf16 of packed pair
    return __uint_as_float(u & 0xffff0000u);
}

// ---------- prep: WcatT[576][128] bf16 (B^T layout), B2T[64][128] bf16 ----------
__global__ void prep_kernel(const float* __restrict__ basis,   // [30][128][64]
                            const float* __restrict__ comp,    // [8][30]
                            const float* __restrict__ root,    // [128][64]
                            const float* __restrict__ w_rel,   // [64][64]
                            const float* __restrict__ w_root,  // [64][64]
                            unsigned short* __restrict__ WcatT, // [576][128] bf16
                            unsigned short* __restrict__ B2T)   // [64][128] bf16
{
    int idx = blockIdx.x * blockDim.x + threadIdx.x;
    const int totalW = NBTOT * GD;          // 73728
    if (idx < totalW) {
        int c = idx / GD;       // output col 0..575
        int i = idx % GD;       // k 0..127
        float v;
        if (c < NREL * H1) {
            int r = c >> 6, o = c & 63;
            float acc = 0.f;
            #pragma unroll 5
            for (int b = 0; b < NBASES; ++b)
                acc += comp[r * NBASES + b] * basis[(b * GD + i) * H1 + o];
            v = acc;
        } else {
            v = root[i * H1 + (c - NREL * H1)];
        }
        WcatT[idx] = f2bf(v);
    } else {
        int j = idx - totalW;               // 0..8191
        if (j < H2 * GD) {
            int o = j / GD, i = j % GD;
            float v = (i < H1) ? w_rel[i * H2 + o] : w_root[(i - H1) * H2 + o];
            B2T[j] = f2bf(v);
        }
    }
}

// ---------- bucket histogram ----------
__global__ __launch_bounds__(512)
void bucket_count(const int* __restrict__ ei, unsigned* __restrict__ bcnt)
{
    __shared__ unsigned l[NBUCK];
    int t = threadIdx.x;
    int c0 = blockIdx.x * ECHUNK;
    int c1 = c0 + ECHUNK; if (c1 > NE) c1 = NE;
    for (int i = t; i < NBUCK; i += 512) l[i] = 0;
    __syncthreads();
    for (int e = c0 + t; e < c1; e += 512)
        atomicAdd(&l[ei[NE + e] >> 8], 1u);
    __syncthreads();
    for (int i = t; i < NBUCK; i += 512)
        if (l[i]) atomicAdd(&bcnt[i], l[i]);
}

// ---------- scan 391 bucket counts ----------
__global__ __launch_bounds__(512)
void bucket_scan(const unsigned* __restrict__ bcnt,
                 unsigned* __restrict__ boff,
                 unsigned* __restrict__ bcur,
                 unsigned* __restrict__ off)
{
    __shared__ unsigned s[512];
    int t = threadIdx.x;
    unsigned v = (t < NBUCK) ? bcnt[t] : 0u;
    s[t] = v;
    __syncthreads();
    for (int st = 1; st < 512; st <<= 1) {
        unsigned u = (t >= st) ? s[t - st] : 0u;
        __syncthreads();
        s[t] += u;
        __syncthreads();
    }
    if (t < NBUCK) { boff[t] = s[t] - v; bcur[t] = s[t] - v; }
    if (t == 511) { boff[NBUCK] = s[511]; off[NN] = s[511]; }
}

// ---------- partition phase A ----------
__global__ __launch_bounds__(512)
void partition_a(const int* __restrict__ ei, const int* __restrict__ et,
                 const float* __restrict__ enorm,
                 unsigned* __restrict__ bcur,
                 uint2* __restrict__ tmp)
{
    __shared__ unsigned lcnt[NBUCK], wbase[NBUCK], lcur[NBUCK];
    int t = threadIdx.x;
    int c0 = blockIdx.x * ECHUNK;
    int c1 = c0 + ECHUNK; if (c1 > NE) c1 = NE;
    for (int i = t; i < NBUCK; i += 512) { lcnt[i] = 0; lcur[i] = 0; }
    __syncthreads();
    for (int e = c0 + t; e < c1; e += 512) {
        int dst = ei[NE + e];
        atomicAdd(&lcnt[dst >> 8], 1u);
    }
    __syncthreads();
    for (int i = t; i < NBUCK; i += 512)
        wbase[i] = atomicAdd(&bcur[i], lcnt[i]);
    __syncthreads();
    for (int e = c0 + t; e < c1; e += 512) {
        int src = ei[e], dst = ei[NE + e], r = et[e];
        int b = dst >> 8;
        unsigned pos = wbase[b] + atomicAdd(&lcur[b], 1u);
        unsigned dl = (unsigned)(dst & (NPB - 1));
        tmp[pos] = make_uint2((dl << 24) | ((unsigned)src << 3) | (unsigned)r,
                              __float_as_uint(enorm[e]));
    }
}

// ---------- partition phase B: count + scan + scatter, writes off/cnt ----------
__global__ __launch_bounds__(512)
void partition_b(const unsigned* __restrict__ boff,
                 const uint2* __restrict__ tmp,
                 uint2* __restrict__ csr,
                 unsigned* __restrict__ off,
                 unsigned* __restrict__ cnt)
{
    __shared__ unsigned lcnt[NPB * NREL];   // 8 KB
    __shared__ unsigned sscan[256];
    __shared__ unsigned lcur[NPB];
    int b = blockIdx.x, t = threadIdx.x;
    int nlo = b * NPB;
    int nn = NN - nlo; if (nn > NPB) nn = NPB;
    for (int i = t; i < NPB * NREL; i += 512) lcnt[i] = 0;
    __syncthreads();
    unsigned bstart = boff[b], bend = boff[b + 1];
    for (unsigned j = bstart + t; j < bend; j += 512) {
        unsigned x = tmp[j].x;
        atomicAdd(&lcnt[((x >> 24) << 3) | (x & 7u)], 1u);
    }
    __syncthreads();
    unsigned tot = 0;
    if (t < 256) {
        if (t < nn) {
            #pragma unroll
            for (int r = 0; r < NREL; ++r) tot += lcnt[t * NREL + r];
        }
        sscan[t] = tot;
    }
    __syncthreads();
    for (int st = 1; st < 256; st <<= 1) {
        unsigned u = (t < 256 && t >= st) ? sscan[t - st] : 0u;
        __syncthreads();
        if (t < 256) sscan[t] += u;
        __syncthreads();
    }
    if (t < nn) {
        unsigned ex = bstart + sscan[t] - tot;
        off[nlo + t] = ex;
        lcur[t] = ex;
        *reinterpret_cast<uint4*>(&cnt[(size_t)(nlo + t) * NREL]) =
            *reinterpret_cast<uint4*>(&lcnt[t * NREL]);
        *reinterpret_cast<uint4*>(&cnt[(size_t)(nlo + t) * NREL + 4]) =
            *reinterpret_cast<uint4*>(&lcnt[t * NREL + 4]);
    }
    __syncthreads();
    for (unsigned j = bstart + t; j < bend; j += 512) {
        uint2 rec = tmp[j];
        unsigned dl = rec.x >> 24;
        unsigned p = atomicAdd(&lcur[dl], 1u);
        csr[p] = make_uint2(rec.x & 0x00FFFFFFu, rec.y);
    }
}

// ---------- MFMA GEMM: BM=128, LDS A+B, reg-prefetched B, raw barriers ----------
// (R10 structure — best measured: 77 us)
template<int MODE>
__global__ __launch_bounds__(256)
void mfma_gemm(const void* __restrict__ Avoid,
               const unsigned short* __restrict__ Bt,
               int M,
               const float* __restrict__ bias,
               unsigned short* __restrict__ y,
               unsigned short* __restrict__ root1b,
               float* __restrict__ out)
{
    constexpr int NT = (MODE == 0) ? 9 : 1;
    __shared__ unsigned short Alds[128 * 128];   // 32 KB, swizzled
    __shared__ unsigned short Blds[64 * 128];    // 16 KB, swizzled

    int tid = threadIdx.x;
    int m0 = blockIdx.x * 128;
    int w = tid >> 6, l = tid & 63;
    int lr = l & 15, lk = l >> 4;

    uint4 breg0, breg1, breg2, breg3;
    {
        int c0 = (0 * 256 + tid) >> 4, s0 = tid & 15;
        int c1 = (1 * 256 + tid) >> 4;
        int c2 = (2 * 256 + tid) >> 4;
        int c3 = (3 * 256 + tid) >> 4;
        breg0 = *reinterpret_cast<const uint4*>(&Bt[(size_t)c0 * GD + s0 * 8]);
        breg1 = *reinterpret_cast<const uint4*>(&Bt[(size_t)c1 * GD + s0 * 8]);
        breg2 = *reinterpret_cast<const uint4*>(&Bt[(size_t)c2 * GD + s0 * 8]);
        breg3 = *reinterpret_cast<const uint4*>(&Bt[(size_t)c3 * GD + s0 * 8]);
    }

    if (MODE == 0) {
        const float* A = (const float*)Avoid;
        #pragma unroll
        for (int p = 0; p < 16; ++p) {
            int f = p * 256 + tid;
            int r = f >> 5;
            int c4 = f & 31;
            float4 av = make_float4(0.f, 0.f, 0.f, 0.f);
            if (m0 + r < M)
                av = *reinterpret_cast<const float4*>(&A[(size_t)(m0 + r) * GD + c4 * 4]);
            ushort4 bv;
            bv.x = f2bf(av.x); bv.y = f2bf(av.y); bv.z = f2bf(av.z); bv.w = f2bf(av.w);
            int slot = (c4 >> 1) ^ (r & 7);
            int byte = r * 256 + (slot << 4) + ((c4 & 1) << 3);
            *reinterpret_cast<ushort4*>(reinterpret_cast<char*>(Alds) + byte) = bv;
        }
    } else {
        const unsigned short* A = (const unsigned short*)Avoid;
        #pragma unroll
        for (int p = 0; p < 8; ++p) {
            int f = p * 256 + tid;
            int r = f >> 4;
            int slot = f & 15;
            uint4 v = make_uint4(0u, 0u, 0u, 0u);
            if (m0 + r < M)
                v = *reinterpret_cast<const uint4*>(&A[(size_t)(m0 + r) * GD + slot * 8]);
            int byte = r * 256 + ((slot ^ (r & 7)) << 4);
            *reinterpret_cast<uint4*>(reinterpret_cast<char*>(Alds) + byte) = v;
        }
    }

    {
        int c = (0 * 256 + tid) >> 4, s = tid & 15;
        *reinterpret_cast<uint4*>(reinterpret_cast<char*>(Blds) + c * 256 + ((s ^ (c & 7)) << 4)) = breg0;
        c = (1 * 256 + tid) >> 4;
        *reinterpret_cast<uint4*>(reinterpret_cast<char*>(Blds) + c * 256 + ((s ^ (c & 7)) << 4)) = breg1;
        c = (2 * 256 + tid) >> 4;
        *reinterpret_cast<uint4*>(reinterpret_cast<char*>(Blds) + c * 256 + ((s ^ (c & 7)) << 4)) = breg2;
        c = (3 * 256 + tid) >> 4;
        *reinterpret_cast<uint4*>(reinterpret_cast<char*>(Blds) + c * 256 + ((s ^ (c & 7)) << 4)) = breg3;
    }
    asm volatile("s_waitcnt lgkmcnt(0)" ::: "memory");
    __builtin_amdgcn_sched_barrier(0);
    __builtin_amdgcn_s_barrier();
    __builtin_amdgcn_sched_barrier(0);

    #pragma unroll 1
    for (int nt = 0; nt < NT; ++nt) {
        if (nt + 1 < NT) {
            int c = (0 * 256 + tid) >> 4, s = tid & 15;
            breg0 = *reinterpret_cast<const uint4*>(&Bt[(size_t)((nt + 1) * 64 + c) * GD + s * 8]);
            c = (1 * 256 + tid) >> 4;
            breg1 = *reinterpret_cast<const uint4*>(&Bt[(size_t)((nt + 1) * 64 + c) * GD + s * 8]);
            c = (2 * 256 + tid) >> 4;
            breg2 = *reinterpret_cast<const uint4*>(&Bt[(size_t)((nt + 1) * 64 + c) * GD + s * 8]);
            c = (3 * 256 + tid) >> 4;
            breg3 = *reinterpret_cast<const uint4*>(&Bt[(size_t)((nt + 1) * 64 + c) * GD + s * 8]);
        }

        f32x4 acc[2][4];
        #pragma unroll
        for (int i = 0; i < 2; ++i)
            #pragma unroll
            for (int j = 0; j < 4; ++j)
                acc[i][j] = (f32x4){0.f, 0.f, 0.f, 0.f};

        #pragma unroll
        for (int ks = 0; ks < 4; ++ks) {
            int q = 4 * ks + lk;
            int sA = q ^ (lr & 7);
            bf16x8 a0 = *reinterpret_cast<const bf16x8*>(
                reinterpret_cast<char*>(Alds) + (w * 32 + 0 * 16 + lr) * 256 + (sA << 4));
            bf16x8 a1 = *reinterpret_cast<const bf16x8*>(
                reinterpret_cast<char*>(Alds) + (w * 32 + 1 * 16 + lr) * 256 + (sA << 4));
            #pragma unroll
            for (int cf = 0; cf < 4; ++cf) {
                bf16x8 b = *reinterpret_cast<const bf16x8*>(
                    reinterpret_cast<char*>(Blds) + (cf * 16 + lr) * 256 + (sA << 4));
                acc[0][cf] = __builtin_amdgcn_mfma_f32_16x16x32_bf16(b, a0, acc[0][cf], 0, 0, 0);
                acc[1][cf] = __builtin_amdgcn_mfma_f32_16x16x32_bf16(b, a1, acc[1][cf], 0, 0, 0);
            }
        }

        #pragma unroll
        for (int rf = 0; rf < 2; ++rf) {
            int row = m0 + w * 32 + rf * 16 + lr;
            if (row < M) {
                #pragma unroll
                for (int cf = 0; cf < 4; ++cf) {
                    int cb = cf * 16 + lk * 4;
                    f32x4 v = acc[rf][cf];
                    if (MODE == 0) {
                        if (nt < 8) {
                            ushort4 pv;
                            pv.x = f2bf(v[0]); pv.y = f2bf(v[1]);
                            pv.z = f2bf(v[2]); pv.w = f2bf(v[3]);
                            *reinterpret_cast<ushort4*>(&y[(size_t)row * 512 + nt * 64 + cb]) = pv;
                        } else {
                            float4 bb = *reinterpret_cast<const float4*>(&bias[cb]);
                            ushort4 pv;
                            pv.x = f2bf(v[0] + bb.x); pv.y = f2bf(v[1] + bb.y);
                            pv.z = f2bf(v[2] + bb.z); pv.w = f2bf(v[3] + bb.w);
                            *reinterpret_cast<ushort4*>(&root1b[(size_t)row * 64 + cb]) = pv;
                        }
                    } else {
                        float4 bb = *reinterpret_cast<const float4*>(&bias[cb]);
                        float4 ov;
                        ov.x = v[0] + bb.x; ov.y = v[1] + bb.y;
                        ov.z = v[2] + bb.z; ov.w = v[3] + bb.w;
                        *reinterpret_cast<float4*>(&out[(size_t)row * 64 + cb]) = ov;
                    }
                }
            }
        }

        if (nt + 1 < NT) {
            asm volatile("s_waitcnt lgkmcnt(0)" ::: "memory");
            __builtin_amdgcn_sched_barrier(0);
            __builtin_amdgcn_s_barrier();
            __builtin_amdgcn_sched_barrier(0);
            int c = (0 * 256 + tid) >> 4, s = tid & 15;
            *reinterpret_cast<uint4*>(reinterpret_cast<char*>(Blds) + c * 256 + ((s ^ (c & 7)) << 4)) = breg0;
            c = (1 * 256 + tid) >> 4;
            *reinterpret_cast<uint4*>(reinterpret_cast<char*>(Blds) + c * 256 + ((s ^ (c & 7)) << 4)) = breg1;
            c = (2 * 256 + tid) >> 4;
            *reinterpret_cast<uint4*>(reinterpret_cast<char*>(Blds) + c * 256 + ((s ^ (c & 7)) << 4)) = breg2;
            c = (3 * 256 + tid) >> 4;
            *reinterpret_cast<uint4*>(reinterpret_cast<char*>(Blds) + c * 256 + ((s ^ (c & 7)) << 4)) = breg3;
            asm volatile("s_waitcnt lgkmcnt(0)" ::: "memory");
            __builtin_amdgcn_sched_barrier(0);
            __builtin_amdgcn_s_barrier();
            __builtin_amdgcn_sched_barrier(0);
        }
    }
}

// ---------- RGCN aggregate v2: wave per node, 4 edge-groups x 16 dim-lanes ----------
// Group g = lane>>4 owns edge i+g; lane sl = lane&15 owns dims sl*4..sl*4+3 (uint2 = 8B).
// Cross-group reduce via shfl_xor(16/32); lanes g==0 write the 128B row.
__global__ void rgcn_aggregate(const unsigned* __restrict__ off,
                               const uint2* __restrict__ csr,
                               const unsigned* __restrict__ cnt,
                               const unsigned short* __restrict__ y,
                               const unsigned short* __restrict__ root1b,
                               unsigned short* __restrict__ abuf)
{
    int gid = blockIdx.x * blockDim.x + threadIdx.x;
    int n = gid >> 6;
    int l = gid & 63;
    if (n >= NN) return;
    int g = l >> 4;
    int sl = l & 15;
    unsigned myc = (l < NREL) ? cnt[(size_t)n * NREL + l] : 1u;
    float myinv = 1.0f / (float)(myc > 0u ? myc : 1u);
    unsigned s = off[n], e = off[n + 1];
    float a0 = 0.f, a1 = 0.f, a2 = 0.f, a3 = 0.f;
    float b0 = 0.f, b1 = 0.f, b2 = 0.f, b3 = 0.f;
    unsigned i = s;
    for (; i + 8 <= e; i += 8) {
        uint2 rA = csr[i + g];
        uint2 rB = csr[i + 4 + g];
        uint2 vA = *reinterpret_cast<const uint2*>(&y[(size_t)rA.x * 64 + sl * 4]);
        uint2 vB = *reinterpret_cast<const uint2*>(&y[(size_t)rB.x * 64 + sl * 4]);
        float wA = __shfl(myinv, (int)(rA.x & 7));
        float wB = __shfl(myinv, (int)(rB.x & 7));
        a0 += wA * bflo(vA.x); a1 += wA * bfhi(vA.x);
        a2 += wA * bflo(vA.y); a3 += wA * bfhi(vA.y);
        b0 += wB * bflo(vB.x); b1 += wB * bfhi(vB.x);
        b2 += wB * bflo(vB.y); b3 += wB * bfhi(vB.y);
    }
    if (i + 4 <= e) {
        uint2 rA = csr[i + g];
        uint2 vA = *reinterpret_cast<const uint2*>(&y[(size_t)rA.x * 64 + sl * 4]);
        float wA = __shfl(myinv, (int)(rA.x & 7));
        a0 += wA * bflo(vA.x); a1 += wA * bfhi(vA.x);
        a2 += wA * bflo(vA.y); a3 += wA * bfhi(vA.y);
        i += 4;
    }
    if (i < e) {                         // tail 1..3 edges, predicated
        unsigned idx = i + (unsigned)g;
        bool valid = idx < e;
        uint2 r = csr[valid ? idx : i];
        uint2 v = *reinterpret_cast<const uint2*>(&y[(size_t)r.x * 64 + sl * 4]);
        float w = __shfl(myinv, (int)(r.x & 7));
        if (!valid) w = 0.f;
        b0 += w * bflo(v.x); b1 += w * bfhi(v.x);
        b2 += w * bflo(v.y); b3 += w * bfhi(v.y);
    }
    a0 += b0; a1 += b1; a2 += b2; a3 += b3;
    a0 += __shfl_xor(a0, 16); a0 += __shfl_xor(a0, 32);
    a1 += __shfl_xor(a1, 16); a1 += __shfl_xor(a1, 32);
    a2 += __shfl_xor(a2, 16); a2 += __shfl_xor(a2, 32);
    a3 += __shfl_xor(a3, 16); a3 += __shfl_xor(a3, 32);
    if (g == 0) {
        uint2 rb = *reinterpret_cast<const uint2*>(&root1b[(size_t)n * 64 + sl * 4]);
        ushort4 pv;
        pv.x = f2bf(bflo(rb.x) + a0);
        pv.y = f2bf(bfhi(rb.x) + a1);
        pv.z = f2bf(bflo(rb.y) + a2);
        pv.w = f2bf(bfhi(rb.y) + a3);
        *reinterpret_cast<ushort4*>(&abuf[(size_t)n * 128 + 64 + sl * 4]) = pv;
    }
}

// ---------- GraphConv aggregate v2: same group structure, per-edge weight in record ----------
__global__ void graph_aggregate(const unsigned* __restrict__ off,
                                const uint2* __restrict__ csr,
                                unsigned short* __restrict__ abuf)
{
    int gid = blockIdx.x * blockDim.x + threadIdx.x;
    int n = gid >> 6;
    int l = gid & 63;
    if (n >= NN) return;
    int g = l >> 4;
    int sl = l & 15;
    unsigned s = off[n], e = off[n + 1];
    float a0 = 0.f, a1 = 0.f, a2 = 0.f, a3 = 0.f;
    float b0 = 0.f, b1 = 0.f, b2 = 0.f, b3 = 0.f;
    unsigned i = s;
    for (; i + 8 <= e; i += 8) {
        uint2 rA = csr[i + g];
        uint2 rB = csr[i + 4 + g];
        uint2 vA = *reinterpret_cast<const uint2*>(&abuf[(size_t)(rA.x >> 3) * 128 + 64 + sl * 4]);
        uint2 vB = *reinterpret_cast<const uint2*>(&abuf[(size_t)(rB.x >> 3) * 128 + 64 + sl * 4]);
        float wA = __uint_as_float(rA.y);
        float wB = __uint_as_float(rB.y);
        a0 += wA * bflo(vA.x); a1 += wA * bfhi(vA.x);
        a2 += wA * bflo(vA.y); a3 += wA * bfhi(vA.y);
        b0 += wB * bflo(vB.x); b1 += wB * bfhi(vB.x);
        b2 += wB * bflo(vB.y); b3 += wB * bfhi(vB.y);
    }
    if (i + 4 <= e) {
        uint2 rA = csr[i + g];
        uint2 vA = *reinterpret_cast<const uint2*>(&abuf[(size_t)(rA.x >> 3) * 128 + 64 + sl * 4]);
        float wA = __uint_as_float(rA.y);
        a0 += wA * bflo(vA.x); a1 += wA * bfhi(vA.x);
        a2 += wA * bflo(vA.y); a3 += wA * bfhi(vA.y);
        i += 4;
    }
    if (i < e) {
        unsigned idx = i + (unsigned)g;
        bool valid = idx < e;
        uint2 r = csr[valid ? idx : i];
        uint2 v = *reinterpret_cast<const uint2*>(&abuf[(size_t)(r.x >> 3) * 128 + 64 + sl * 4]);
        float w = valid ? __uint_as_float(r.y) : 0.f;
        b0 += w * bflo(v.x); b1 += w * bfhi(v.x);
        b2 += w * bflo(v.y); b3 += w * bfhi(v.y);
    }
    a0 += b0; a1 += b1; a2 += b2; a3 += b3;
    a0 += __shfl_xor(a0, 16); a0 += __shfl_xor(a0, 32);
    a1 += __shfl_xor(a1, 16); a1 += __shfl_xor(a1, 32);
    a2 += __shfl_xor(a2, 16); a2 += __shfl_xor(a2, 32);
    a3 += __shfl_xor(a3, 16); a3 += __shfl_xor(a3, 32);
    if (g == 0) {
        ushort4 pv;
        pv.x = f2bf(a0); pv.y = f2bf(a1); pv.z = f2bf(a2); pv.w = f2bf(a3);
        *reinterpret_cast<ushort4*>(&abuf[(size_t)n * 128 + sl * 4]) = pv;
    }
}

extern "C" void kernel_launch(void* const* d_in, const int* in_sizes, int n_in,
                              void* d_out, int out_size, void* d_ws, size_t ws_size,
                              hipStream_t stream)
{
    const float* node_features = (const float*)d_in[0];
    const int*   edge_index    = (const int*)d_in[1];
    const float* edge_norm     = (const float*)d_in[2];
    const int*   edge_type     = (const int*)d_in[3];
    const float* basis         = (const float*)d_in[4];
    const float* comp          = (const float*)d_in[5];
    const float* root          = (const float*)d_in[6];
    const float* bias1         = (const float*)d_in[7];
    const float* w_rel         = (const float*)d_in[8];
    const float* b_rel         = (const float*)d_in[9];
    const float* w_root        = (const float*)d_in[10];
    float* out = (float*)d_out;

    char* ws = (char*)d_ws;
    size_t o = 0;
    auto alloc = [&](size_t bytes) -> void* {
        o = (o + 511) & ~(size_t)511;
        void* p = ws + o;
        o += bytes;
        return p;
    };
    unsigned short* WcatT = (unsigned short*)alloc((size_t)NBTOT * GD * 2);
    unsigned short* B2T   = (unsigned short*)alloc((size_t)H2 * GD * 2);
    unsigned* cnt      = (unsigned*)alloc((size_t)NN * NREL * 4);
    unsigned* off_     = (unsigned*)alloc((size_t)(NN + 1) * 4);
    unsigned* bcnt     = (unsigned*)alloc((size_t)NBUCK * 4);
    unsigned* boff     = (unsigned*)alloc((size_t)(NBUCK + 1) * 4);
    unsigned* bcur     = (unsigned*)alloc((size_t)NBUCK * 4);
    uint2*    csr      = (uint2*)alloc((size_t)NE * 8);
    unsigned short* y  = (unsigned short*)alloc((size_t)NN * 512 * 2);
    unsigned short* root1b = (unsigned short*)alloc((size_t)NN * 64 * 2);
    unsigned short* abuf = (unsigned short*)alloc((size_t)NN * 128 * 2);
    uint2*    tmp      = (uint2*)abuf;   // alias: tmp dead before abuf's first write

    hipMemsetAsync(bcnt, 0, (size_t)NBUCK * 4, stream);

    prep_kernel<<<(NBTOT * GD + H2 * GD + 255) / 256, 256, 0, stream>>>(
        basis, comp, root, w_rel, w_root, WcatT, B2T);

    bucket_count<<<NWGA, 512, 0, stream>>>(edge_index, bcnt);
    bucket_scan<<<1, 512, 0, stream>>>(bcnt, boff, bcur, off_);
    partition_a<<<NWGA, 512, 0, stream>>>(edge_index, edge_type, edge_norm, bcur, tmp);
    partition_b<<<NBUCK, 512, 0, stream>>>(boff, tmp, csr, off_, cnt);

    int gblk = (NN + 127) / 128;   // 782
    mfma_gemm<0><<<gblk, 256, 0, stream>>>(node_features, WcatT, NN, bias1, y, root1b, nullptr);

    rgcn_aggregate<<<(NN * 64 + 255) / 256, 256, 0, stream>>>(off_, csr, cnt, y, root1b, abuf);

    graph_aggregate<<<(NN * 64 + 255) / 256, 256, 0, stream>>>(off_, csr, abuf);

    mfma_gemm<1><<<gblk, 256, 0, stream>>>(abuf, B2T, NN, b_rel, nullptr, nullptr, out);
}